// Round 2
// baseline (250.317 us; speedup 1.0000x reference)
//
#include <hip/hip_runtime.h>

#define NXD 4096
#define NYD 4096
#define ROWS 4

typedef float f32x4 __attribute__((ext_vector_type(4)));

__global__ __launch_bounds__(256) void DiffReactParamPDE_85478439125433_kernel(
    const float* __restrict__ state,
    const float* __restrict__ bc,
    const float* __restrict__ a_org,
    const float* __restrict__ b_org,
    const float* __restrict__ k_org,
    float* __restrict__ out)
{
    const float inv_dx2 = 100.0f;  // 1/(0.1*0.1)

    // sigmoid(x) * 0.01 — uniform scalars
    const float a = 0.01f / (1.0f + expf(-a_org[0]));
    const float b = 0.01f / (1.0f + expf(-b_org[0]));
    const float k = 0.01f / (1.0f + expf(-k_org[0]));

    // bc layout (1,2,4): [U: left,right,top,bottom | V: left,right,top,bottom]
    const float uL = bc[0], uR = bc[1], uT = bc[2], uB = bc[3];
    const float vL = bc[4], vR = bc[5], vT = bc[6], vB = bc[7];

    const int j0 = (blockIdx.x * 256 + threadIdx.x) * 4;  // first column of this thread
    const int i0 = blockIdx.y * ROWS;                     // first output row

    const float* __restrict__ U = state;
    const float* __restrict__ V = state + (size_t)NXD * NYD;
    float* __restrict__ dU = out;
    float* __restrict__ dV = out + (size_t)NXD * NYD;

    const size_t rowbase = (size_t)i0 * NYD + j0;

    // ---- batch ALL loads into registers first (maximize loads in flight) ----
    float4 u[ROWS + 2], v[ROWS + 2];   // rows i0-1 .. i0+ROWS
#pragma unroll
    for (int r = 0; r < ROWS + 2; ++r) {
        const int row = i0 - 1 + r;
        if (row >= 0 && row < NXD) {
            const size_t bofs = (size_t)row * NYD + j0;
            u[r] = *(const float4*)(U + bofs);
            v[r] = *(const float4*)(V + bofs);
        } else if (row < 0) {
            u[r] = make_float4(uT, uT, uT, uT);
            v[r] = make_float4(vT, vT, vT, vT);
        } else {
            u[r] = make_float4(uB, uB, uB, uB);
            v[r] = make_float4(vB, vB, vB, vB);
        }
    }

    float ulft[ROWS], urgt[ROWS], vlft[ROWS], vrgt[ROWS];
#pragma unroll
    for (int r = 0; r < ROWS; ++r) {
        const size_t bo = rowbase + (size_t)r * NYD;
        ulft[r] = (j0 > 0)       ? U[bo - 1] : uL;
        urgt[r] = (j0 + 4 < NYD) ? U[bo + 4] : uR;
        vlft[r] = (j0 > 0)       ? V[bo - 1] : vL;
        vrgt[r] = (j0 + 4 < NYD) ? V[bo + 4] : vR;
    }

    // ---- compute + store ----
#pragma unroll
    for (int r = 0; r < ROWS; ++r) {
        const float4 cu = u[r + 1], cv = v[r + 1];
        const float4 au = u[r],     bu = u[r + 2];
        const float4 av = v[r],     bv = v[r + 2];

        const float lu0 = (au.x + bu.x + ulft[r] + cu.y - 4.0f * cu.x) * inv_dx2;
        const float lu1 = (au.y + bu.y + cu.x    + cu.z - 4.0f * cu.y) * inv_dx2;
        const float lu2 = (au.z + bu.z + cu.y    + cu.w - 4.0f * cu.z) * inv_dx2;
        const float lu3 = (au.w + bu.w + cu.z + urgt[r] - 4.0f * cu.w) * inv_dx2;

        const float lv0 = (av.x + bv.x + vlft[r] + cv.y - 4.0f * cv.x) * inv_dx2;
        const float lv1 = (av.y + bv.y + cv.x    + cv.z - 4.0f * cv.y) * inv_dx2;
        const float lv2 = (av.z + bv.z + cv.y    + cv.w - 4.0f * cv.z) * inv_dx2;
        const float lv3 = (av.w + bv.w + cv.z + vrgt[r] - 4.0f * cv.w) * inv_dx2;

        f32x4 duo, dvo;
        duo.x = a * lu0 + cu.x - cu.x * cu.x * cu.x - cv.x - k;
        duo.y = a * lu1 + cu.y - cu.y * cu.y * cu.y - cv.y - k;
        duo.z = a * lu2 + cu.z - cu.z * cu.z * cu.z - cv.z - k;
        duo.w = a * lu3 + cu.w - cu.w * cu.w * cu.w - cv.w - k;

        dvo.x = b * lv0 + cu.x - cv.x;
        dvo.y = b * lv1 + cu.y - cv.y;
        dvo.z = b * lv2 + cu.z - cv.z;
        dvo.w = b * lv3 + cu.w - cv.w;

        const size_t bo = rowbase + (size_t)r * NYD;
        // output is never re-read: nontemporal stores keep L2 for stencil reads
        __builtin_nontemporal_store(duo, (f32x4*)(dU + bo));
        __builtin_nontemporal_store(dvo, (f32x4*)(dV + bo));
    }
}

extern "C" void kernel_launch(void* const* d_in, const int* in_sizes, int n_in,
                              void* d_out, int out_size, void* d_ws, size_t ws_size,
                              hipStream_t stream) {
    const float* state = (const float*)d_in[0];
    const float* bc    = (const float*)d_in[1];
    const float* a_org = (const float*)d_in[2];
    const float* b_org = (const float*)d_in[3];
    const float* k_org = (const float*)d_in[4];
    float* out = (float*)d_out;

    // 256 threads × 4 cols = 1024 cols/block → 4 blocks in x; 4096/ROWS blocks in y
    dim3 block(256, 1, 1);
    dim3 grid(NYD / (4 * 256), NXD / ROWS, 1);
    DiffReactParamPDE_85478439125433_kernel<<<grid, block, 0, stream>>>(
        state, bc, a_org, b_org, k_org, out);
}

// Round 3
// 245.186 us; speedup vs baseline: 1.0209x; 1.0209x over previous
//
#include <hip/hip_runtime.h>

#define NXD 4096
#define NYD 4096
#define ROWS 8

typedef float f32x4 __attribute__((ext_vector_type(4)));

__global__ __launch_bounds__(256) void DiffReactParamPDE_85478439125433_kernel(
    const float* __restrict__ state,
    const float* __restrict__ bc,
    const float* __restrict__ a_org,
    const float* __restrict__ b_org,
    const float* __restrict__ k_org,
    float* __restrict__ out)
{
    const float inv_dx2 = 100.0f;

    const float a = 0.01f / (1.0f + expf(-a_org[0]));
    const float b = 0.01f / (1.0f + expf(-b_org[0]));
    const float k = 0.01f / (1.0f + expf(-k_org[0]));

    // bc (1,2,4): [U: L,R,T,B | V: L,R,T,B]
    const float uL = bc[0], uR = bc[1], uT = bc[2], uB = bc[3];
    const float vL = bc[4], vR = bc[5], vT = bc[6], vB = bc[7];

    const int lane = threadIdx.x & 63;
    const int j0 = (blockIdx.x * 256 + threadIdx.x) * 4;  // first col of this thread
    const int i0 = blockIdx.y * ROWS;                     // first output row

    const float* __restrict__ U = state;
    const float* __restrict__ V = state + (size_t)NXD * NYD;
    float* __restrict__ dU = out;
    float* __restrict__ dV = out + (size_t)NXD * NYD;

    const float4 fuT = make_float4(uT, uT, uT, uT), fuB = make_float4(uB, uB, uB, uB);
    const float4 fvT = make_float4(vT, vT, vT, vT), fvB = make_float4(vB, vB, vB, vB);

#define LD4(P, ROW) (*(const float4*)((P) + (size_t)(ROW) * NYD + j0))

    // ---- rolling registers: rows r-1 (m), r (c), r+1 (p) ----
    float4 um, uc, up, vm, vc, vp;
    if (i0 > 0) { um = LD4(U, i0 - 1); vm = LD4(V, i0 - 1); }
    else        { um = fuT;            vm = fvT; }
    uc = LD4(U, i0); vc = LD4(V, i0);
    if (i0 + 1 < NXD) { up = LD4(U, i0 + 1); vp = LD4(V, i0 + 1); }
    else              { up = fuB;            vp = fvB; }

    // edge scalars for the current compute row (only lanes 0 / 63 use them)
    float eLu = uL, eRu = uR, eLv = vL, eRv = vR;
    if (lane == 0 && j0 > 0) {
        eLu = U[(size_t)i0 * NYD + j0 - 1];
        eLv = V[(size_t)i0 * NYD + j0 - 1];
    }
    if (lane == 63 && j0 + 4 < NYD) {
        eRu = U[(size_t)i0 * NYD + j0 + 4];
        eRv = V[(size_t)i0 * NYD + j0 + 4];
    }

#pragma unroll
    for (int r = 0; r < ROWS; ++r) {
        const int row = i0 + r;

        // ---- prefetch row+2 (next iteration's 'p') and edges for row+1 ----
        float4 un = fuB, vn = fvB;
        float eLu_n = uL, eRu_n = uR, eLv_n = vL, eRv_n = vR;
        if (r < ROWS - 1) {
            const int rn = row + 2;
            if (rn < NXD) { un = LD4(U, rn); vn = LD4(V, rn); }
            if (lane == 0 && j0 > 0) {
                eLu_n = U[(size_t)(row + 1) * NYD + j0 - 1];
                eLv_n = V[(size_t)(row + 1) * NYD + j0 - 1];
            }
            if (lane == 63 && j0 + 4 < NYD) {
                eRu_n = U[(size_t)(row + 1) * NYD + j0 + 4];
                eRv_n = V[(size_t)(row + 1) * NYD + j0 + 4];
            }
        }

        // ---- horizontal neighbors via cross-lane shuffle (no gathers) ----
        float ulft = __shfl_up(uc.w, 1);   if (lane == 0)  ulft = eLu;
        float urgt = __shfl_down(uc.x, 1); if (lane == 63) urgt = eRu;
        float vlft = __shfl_up(vc.w, 1);   if (lane == 0)  vlft = eLv;
        float vrgt = __shfl_down(vc.x, 1); if (lane == 63) vrgt = eRv;

        // ---- Laplacians ----
        const float lu0 = (um.x + up.x + ulft + uc.y - 4.0f * uc.x) * inv_dx2;
        const float lu1 = (um.y + up.y + uc.x + uc.z - 4.0f * uc.y) * inv_dx2;
        const float lu2 = (um.z + up.z + uc.y + uc.w - 4.0f * uc.z) * inv_dx2;
        const float lu3 = (um.w + up.w + uc.z + urgt - 4.0f * uc.w) * inv_dx2;

        const float lv0 = (vm.x + vp.x + vlft + vc.y - 4.0f * vc.x) * inv_dx2;
        const float lv1 = (vm.y + vp.y + vc.x + vc.z - 4.0f * vc.y) * inv_dx2;
        const float lv2 = (vm.z + vp.z + vc.y + vc.w - 4.0f * vc.z) * inv_dx2;
        const float lv3 = (vm.w + vp.w + vc.z + vrgt - 4.0f * vc.w) * inv_dx2;

        f32x4 duo, dvo;
        duo.x = a * lu0 + uc.x - uc.x * uc.x * uc.x - vc.x - k;
        duo.y = a * lu1 + uc.y - uc.y * uc.y * uc.y - vc.y - k;
        duo.z = a * lu2 + uc.z - uc.z * uc.z * uc.z - vc.z - k;
        duo.w = a * lu3 + uc.w - uc.w * uc.w * uc.w - vc.w - k;

        dvo.x = b * lv0 + uc.x - vc.x;
        dvo.y = b * lv1 + uc.y - vc.y;
        dvo.z = b * lv2 + uc.z - vc.z;
        dvo.w = b * lv3 + uc.w - vc.w;

        const size_t bo = (size_t)row * NYD + j0;
        __builtin_nontemporal_store(duo, (f32x4*)(dU + bo));
        __builtin_nontemporal_store(dvo, (f32x4*)(dV + bo));

        // ---- shift the rolling window ----
        um = uc; uc = up; up = un;
        vm = vc; vc = vp; vp = vn;
        eLu = eLu_n; eRu = eRu_n; eLv = eLv_n; eRv = eRv_n;
    }
#undef LD4
}

extern "C" void kernel_launch(void* const* d_in, const int* in_sizes, int n_in,
                              void* d_out, int out_size, void* d_ws, size_t ws_size,
                              hipStream_t stream) {
    const float* state = (const float*)d_in[0];
    const float* bc    = (const float*)d_in[1];
    const float* a_org = (const float*)d_in[2];
    const float* b_org = (const float*)d_in[3];
    const float* k_org = (const float*)d_in[4];
    float* out = (float*)d_out;

    // 256 threads × 4 cols = 1024 cols/block → 4 x-blocks; 4096/ROWS y-blocks
    dim3 block(256, 1, 1);
    dim3 grid(NYD / (4 * 256), NXD / ROWS, 1);
    DiffReactParamPDE_85478439125433_kernel<<<grid, block, 0, stream>>>(
        state, bc, a_org, b_org, k_org, out);
}